// Round 1
// baseline (176.299 us; speedup 1.0000x reference)
//
#include <hip/hip_runtime.h>
#include <math.h>

#define Tc 1024
#define Dc 256
#define Hc 8
#define Cc 16
#define LUTN 256

typedef __attribute__((ext_vector_type(8))) short short8;
typedef __attribute__((ext_vector_type(4))) float f32x4;

__device__ __forceinline__ unsigned bf16u(float x) {   // RNE
    unsigned u = __float_as_uint(x);
    return (u + 0x7FFFu + ((u >> 16) & 1u)) >> 16;
}
__device__ __forceinline__ unsigned pk2(float lo, float hi) {
    return bf16u(lo) | (bf16u(hi) << 16);
}
__device__ __forceinline__ unsigned pk2t(float lo, float hi) {  // truncating, 1 inst
    return __builtin_amdgcn_perm(__float_as_uint(hi), __float_as_uint(lo), 0x07060302u);
}
__device__ __forceinline__ float upk(unsigned v) { return __uint_as_float(v << 16); }
__device__ __forceinline__ float upkh(unsigned v) { return __uint_as_float(v & 0xffff0000u); }

// ---------------- K0: cast weights to bf16; build PWL LUT; pack rel+mask ----
// blocks [0,320): weight casts. block 320: LUT. blocks [321,4417): Dm pack.
__global__ __launch_bounds__(256) void cast_all(
    const float* __restrict__ rel, const int* __restrict__ msk,
    const float* __restrict__ Wq, const float* __restrict__ Wk,
    const float* __restrict__ Wv, const float* __restrict__ Wo,
    const float* __restrict__ Wf,
    const float* __restrict__ pw1, const float* __restrict__ pb1,
    const float* __restrict__ pw2, const float* __restrict__ pb2,
    ushort* __restrict__ Wqkvc, ushort* __restrict__ Woc,
    ushort* __restrict__ Wfc, ushort* __restrict__ LUTb,
    ushort* __restrict__ Dm)
{
    const int bid = blockIdx.x;
    const int tid = threadIdx.x;
    if (bid == 320) {
        const int bin = tid;
        const float d0 = bin * (1.f / LUTN), d1 = (bin + 1) * (1.f / LUTN);
        for (int h = 0; h < Hc; ++h) {
            float y0 = pb2[h], y1 = pb2[h];
#pragma unroll
            for (int c = 0; c < Cc; ++c) {
                float w1 = pw1[h * Cc + c], b1 = pb1[h * Cc + c], w2 = pw2[h * Cc + c];
                float h0 = fmaf(w1, d0, b1), h1 = fmaf(w1, d1, b1);
                y0 = fmaf(w2, h0 >= 0.f ? h0 : 0.01f * h0, y0);
                y1 = fmaf(w2, h1 >= 0.f ? h1 : 0.01f * h1, y1);
            }
            float a = (y1 - y0) * (float)LUTN;
            float b = y0 - a * d0;
            // per-head-PAIR tables: 2 heads x 256 bins x (a,b)
            LUTb[(h >> 1) * 1024 + bin * 4 + (h & 1) * 2]     = (ushort)bf16u(a);
            LUTb[(h >> 1) * 1024 + bin * 4 + (h & 1) * 2 + 1] = (ushort)bf16u(b);
        }
        return;
    }
    if (bid < 320) {
        const int e = bid * 1024 + tid * 4;
        const float* src; ushort* dst; int off;
        if      (e <  65536) { src = Wq; dst = Wqkvc;          off = e; }
        else if (e < 131072) { src = Wk; dst = Wqkvc + 65536;  off = e - 65536; }
        else if (e < 196608) { src = Wv; dst = Wqkvc + 131072; off = e - 131072; }
        else if (e < 262144) { src = Wo; dst = Woc;            off = e - 196608; }
        else                 { src = Wf; dst = Wfc;            off = e - 262144; }
        float4 v = *(const float4*)(src + off);
        uint2 p; p.x = pk2(v.x, v.y); p.y = pk2(v.z, v.w);
        *(uint2*)(dst + off) = p;
        return;
    }
    // Dm pack: bf16(rel), masked -> -1.0f (0xBF80)
    const int idx = (bid - 321) * 1024 + tid * 4;
    float4 d4 = *(const float4*)(rel + idx);
    int4   m4 = *(const int4*)(msk + idx);
    uint2 p;
    p.x = (m4.x ? 0xBF80u : bf16u(d4.x)) | ((m4.y ? 0xBF80u : bf16u(d4.y)) << 16);
    p.y = (m4.z ? 0xBF80u : bf16u(d4.z)) | ((m4.w ? 0xBF80u : bf16u(d4.w)) << 16);
    *(uint2*)(Dm + idx) = p;
}

// ---------------- K1: QKV direct-MFMA GEMM (no LDS, no barriers) ------------
// grid (256, 3), block 256 = 4 waves. Wave: C tile 16 rows x 64 cols.
// A-operand read from x (fp32) and packed bf16 in-register (RNE, == old Xc).
__global__ __launch_bounds__(256) void qkv_direct(
    const float* __restrict__ x, const ushort* __restrict__ Wqkv,
    ushort* __restrict__ Qb, ushort* __restrict__ Kb, ushort* __restrict__ Vt)
{
    const int tid = threadIdx.x;
    const int w = tid >> 6;
    const int l = tid & 63;
    const int u = l & 15, g = l >> 4;
    const int rbase = blockIdx.x * 16;
    const int cb = (blockIdx.y * 4 + w) * 64;     // 0..704

    f32x4 acc[4];
#pragma unroll
    for (int nt = 0; nt < 4; ++nt) acc[nt] = (f32x4){0.f, 0.f, 0.f, 0.f};

    const float* arow = x + (size_t)(rbase + u) * 256 + g * 8;
#pragma unroll 2
    for (int k0 = 0; k0 < 256; k0 += 32) {
        float4 a0 = *(const float4*)(arow + k0);
        float4 a1 = *(const float4*)(arow + k0 + 4);
        union { short8 s; unsigned wds[4]; } A;
        A.wds[0] = pk2(a0.x, a0.y); A.wds[1] = pk2(a0.z, a0.w);
        A.wds[2] = pk2(a1.x, a1.y); A.wds[3] = pk2(a1.z, a1.w);
#pragma unroll
        for (int nt = 0; nt < 4; ++nt) {
            short8 bfr = *(const short8*)(Wqkv + (size_t)(cb + nt * 16 + u) * 256 + k0 + g * 8);
            acc[nt] = __builtin_amdgcn_mfma_f32_16x16x32_bf16(A.s, bfr, acc[nt], 0, 0, 0);
        }
    }

    const int mat = cb >> 8;
    const int fcb = cb & 255;
    if (mat < 2) {
        ushort* Out = (mat == 0) ? Qb : Kb;
#pragma unroll
        for (int hp = 0; hp < 2; ++hp) {          // two heads per wave tile
            const int head = (fcb >> 5) + hp;
#pragma unroll
            for (int reg = 0; reg < 4; ++reg) {
                float ss = acc[2 * hp][reg] * acc[2 * hp][reg]
                         + acc[2 * hp + 1][reg] * acc[2 * hp + 1][reg];
                ss += __shfl_xor(ss, 1, 64);
                ss += __shfl_xor(ss, 2, 64);
                ss += __shfl_xor(ss, 4, 64);
                ss += __shfl_xor(ss, 8, 64);
                float scn = 1.f / fmaxf(sqrtf(ss), 1e-12f);
                const int t = rbase + 4 * g + reg;
                const int bb = t >> 10, tt = t & 1023;
                const size_t base = ((size_t)(bb * 8 + head) * Tc + tt) * 32;
                Out[base + u]      = (ushort)bf16u(acc[2 * hp][reg] * scn);
                Out[base + 16 + u] = (ushort)bf16u(acc[2 * hp + 1][reg] * scn);
            }
        }
    } else {
#pragma unroll
        for (int nt = 0; nt < 4; ++nt) {
            const int head = (fcb >> 5) + (nt >> 1);
            const int vt = nt & 1;
#pragma unroll
            for (int reg = 0; reg < 4; ++reg) {
                const int s = rbase + 4 * g + reg;
                const int bb = s >> 10, ss = s & 1023;
                const int bh = bb * 8 + head;
                Vt[(((size_t)bh * 32 + (ss >> 5)) * 2 + vt) * 512 + u * 32 + (ss & 31)] =
                    (ushort)bf16u(acc[nt][reg]);
            }
        }
    }
}

// ---------------- K2: MFMA flash attention ----------------------------------
// grid (T/16, B, 4). block 256 = 4 waves; wave w covers s in [w*256, +256).
// 2 heads per block (halved regs, doubled grid); d+mask read packed bf16.
__global__ __launch_bounds__(256) void attn_mfma(
    const ushort* __restrict__ Qb, const ushort* __restrict__ Kb,
    const ushort* __restrict__ Vt, const ushort* __restrict__ Dm,
    const ushort* __restrict__ LUTb,
    ushort* __restrict__ Yb)
{
    const int tid = threadIdx.x;
    const int w = tid >> 6;
    const int l = tid & 63;
    const int u = l & 15;
    const int g = l >> 4;
    const int t0 = blockIdx.x * 16;
    const int b = blockIdx.y;
    const int hg = blockIdx.z;                    // head pair 0..3

    __shared__ __align__(16) ushort lut_s[1024];         // 2 KB (2 heads)
    __shared__ __align__(16) unsigned plds[4 * 320];     // 5 KB
    __shared__ __align__(16) ushort comb[4 * 16 * 72];   // 9 KB bf16 partials
    __shared__ float rs_s[8 * 16];                       // 512 B

    if (tid < 128)
        *(uint4*)(lut_s + tid * 8) = *(const uint4*)(LUTb + hg * 1024 + tid * 8);

    const int bh0 = b * 8 + hg * 2;
    short8 qf[2];
#pragma unroll
    for (int hi = 0; hi < 2; ++hi)
        qf[hi] = *(const short8*)(Qb + (((size_t)(bh0 + hi) * Tc + t0 + u) * 32 + g * 8));

    const short8 ones = (short8){0x3F80, 0x3F80, 0x3F80, 0x3F80,
                                 0x3F80, 0x3F80, 0x3F80, 0x3F80};

    f32x4 oacc[2][2];
    f32x4 rsacc[2];
#pragma unroll
    for (int hi = 0; hi < 2; ++hi) {
        oacc[hi][0] = (f32x4){0.f, 0.f, 0.f, 0.f};
        oacc[hi][1] = (f32x4){0.f, 0.f, 0.f, 0.f};
        rsacc[hi]   = (f32x4){0.f, 0.f, 0.f, 0.f};
    }

    unsigned* pwb = plds + w * 320;
    const size_t dbase = (size_t)b * Tc * Tc;

    __syncthreads();   // lut staged

    const int s_begin = w * 256;
    unsigned dmv[4];
#pragma unroll
    for (int reg = 0; reg < 4; ++reg) {
        const int t = t0 + 4 * g + reg;
        dmv[reg] = *(const unsigned*)(Dm + dbase + (size_t)t * Tc + s_begin + 2 * u);
    }

    for (int sc = s_begin; sc < s_begin + 256; sc += 32) {
        // prefetch next iteration's packed d
        unsigned dmn[4] = {0, 0, 0, 0};
        const int nx = sc + 32;
        if (nx < s_begin + 256) {
#pragma unroll
            for (int reg = 0; reg < 4; ++reg) {
                const int t = t0 + 4 * g + reg;
                dmn[reg] = *(const unsigned*)(Dm + dbase + (size_t)t * Tc + nx + 2 * u);
            }
        }
        float dA[4], dB[4];
#pragma unroll
        for (int reg = 0; reg < 4; ++reg) {
            dA[reg] = upk(dmv[reg]);      // masked -> -1.0
            dB[reg] = upkh(dmv[reg]);
        }
        float biasA[4][2], biasB[4][2];
#pragma unroll
        for (int reg = 0; reg < 4; ++reg) {
            int iA = (int)(dA[reg] * (float)LUTN);
            int iB = (int)(dB[reg] * (float)LUTN);
            iA = iA < 0 ? 0 : (iA > LUTN - 1 ? LUTN - 1 : iA);
            iB = iB < 0 ? 0 : (iB > LUTN - 1 ? LUTN - 1 : iB);
            uint2 wA = *(const uint2*)(lut_s + iA * 4);
            uint2 wB = *(const uint2*)(lut_s + iB * 4);
            biasA[reg][0] = fmaf(upk(wA.x), dA[reg], upkh(wA.x));
            biasA[reg][1] = fmaf(upk(wA.y), dA[reg], upkh(wA.y));
            biasB[reg][0] = fmaf(upk(wB.x), dB[reg], upkh(wB.x));
            biasB[reg][1] = fmaf(upk(wB.y), dB[reg], upkh(wB.y));
        }
#pragma unroll
        for (int hi = 0; hi < 2; ++hi) {
            const size_t kb = ((size_t)(bh0 + hi) * Tc + sc + 2 * u) * 32 + g * 8;
            short8 kfA = *(const short8*)(Kb + kb);
            short8 kfB = *(const short8*)(Kb + kb + 32);
            const f32x4 z4 = (f32x4){0.f, 0.f, 0.f, 0.f};
            f32x4 sA = __builtin_amdgcn_mfma_f32_16x16x32_bf16(qf[hi], kfA, z4, 0, 0, 0);
            f32x4 sB = __builtin_amdgcn_mfma_f32_16x16x32_bf16(qf[hi], kfB, z4, 0, 0, 0);
#pragma unroll
            for (int reg = 0; reg < 4; ++reg) {
                float zA = (dA[reg] < 0.f) ? 0.f : __expf(sA[reg] - biasA[reg][hi]);
                float zB = (dB[reg] < 0.f) ? 0.f : __expf(sB[reg] - biasB[reg][hi]);
                pwb[(4 * g + reg) * 20 + u] = pk2t(zA, zB);
            }
            short8 pf = *(const short8*)((const char*)pwb + u * 80 + g * 16);
            const ushort* vb = Vt + ((size_t)(bh0 + hi) * 32 + (sc >> 5)) * 1024;
            short8 vf0 = *(const short8*)(vb + u * 32 + g * 8);
            short8 vf1 = *(const short8*)(vb + 512 + u * 32 + g * 8);
            oacc[hi][0] = __builtin_amdgcn_mfma_f32_16x16x32_bf16(pf, vf0, oacc[hi][0], 0, 0, 0);
            oacc[hi][1] = __builtin_amdgcn_mfma_f32_16x16x32_bf16(pf, vf1, oacc[hi][1], 0, 0, 0);
            rsacc[hi]   = __builtin_amdgcn_mfma_f32_16x16x32_bf16(pf, ones, rsacc[hi], 0, 0, 0);
        }
#pragma unroll
        for (int reg = 0; reg < 4; ++reg) dmv[reg] = dmn[reg];
    }

    // rowsums already reduced by the ones-MFMA (all u columns equal)
#pragma unroll
    for (int hi = 0; hi < 2; ++hi)
        if (u == 0) {
#pragma unroll
            for (int reg = 0; reg < 4; ++reg)
                rs_s[(w * 2 + hi) * 16 + 4 * g + reg] = rsacc[hi][reg];
        }
#pragma unroll
    for (int hi = 0; hi < 2; ++hi)
#pragma unroll
        for (int vt = 0; vt < 2; ++vt)
#pragma unroll
            for (int reg = 0; reg < 4; ++reg)
                comb[w * 1152 + (4 * g + reg) * 72 + hi * 32 + vt * 16 + u] =
                    (ushort)(__float_as_uint(oacc[hi][vt][reg]) >> 16);
    __syncthreads();

    // combine 4 waves, normalize, store bf16 Y (16 rows x 64 cols -> 128 thr)
    if (tid < 128) {
        const int tl = tid >> 3;
        const int f0 = (tid & 7) * 8;
        const int hl = f0 >> 5;
        float rstot = rs_s[hl * 16 + tl] + rs_s[(2 + hl) * 16 + tl]
                    + rs_s[(4 + hl) * 16 + tl] + rs_s[(6 + hl) * 16 + tl];
        float inv = 1.f / (rstot + 1e-5f);
        float o[8];
#pragma unroll
        for (int k = 0; k < 8; ++k) o[k] = 0.f;
#pragma unroll
        for (int ww = 0; ww < 4; ++ww) {
            uint4 pv = *(const uint4*)&comb[ww * 1152 + tl * 72 + f0];
            o[0] += upk(pv.x); o[1] += upkh(pv.x);
            o[2] += upk(pv.y); o[3] += upkh(pv.y);
            o[4] += upk(pv.z); o[5] += upkh(pv.z);
            o[6] += upk(pv.w); o[7] += upkh(pv.w);
        }
        uint4 pwv;
        pwv.x = pk2(o[0] * inv, o[1] * inv); pwv.y = pk2(o[2] * inv, o[3] * inv);
        pwv.z = pk2(o[4] * inv, o[5] * inv); pwv.w = pk2(o[6] * inv, o[7] * inv);
        *(uint4*)(Yb + ((size_t)b * Tc + t0 + tl) * Dc + hg * 64 + f0) = pwv;
    }
}

// ---------------- K3/K4: direct-MFMA GEMM + bias (+lrelu) + residual + LN ---
// grid 256, block 256 = 4 waves; block = 16 rows x 256 cols (full row).
__global__ __launch_bounds__(256) void gemm_ln(
    const ushort* __restrict__ A, const ushort* __restrict__ W,
    const float* __restrict__ bias,
    const float* __restrict__ resF, const ushort* __restrict__ resB,
    const float* __restrict__ gam, const float* __restrict__ bet,
    float* __restrict__ outF, ushort* __restrict__ outB, int act)
{
    const int tid = threadIdx.x;
    const int w = tid >> 6;
    const int l = tid & 63;
    const int u = l & 15, g = l >> 4;
    const int rbase = blockIdx.x * 16;

    __shared__ float red1[64], red2[64];

    f32x4 acc[4];
#pragma unroll
    for (int nt = 0; nt < 4; ++nt) acc[nt] = (f32x4){0.f, 0.f, 0.f, 0.f};

    const ushort* arow = A + (size_t)(rbase + u) * 256 + g * 8;
#pragma unroll 2
    for (int k0 = 0; k0 < 256; k0 += 32) {
        short8 af = *(const short8*)(arow + k0);
#pragma unroll
        for (int nt = 0; nt < 4; ++nt) {
            short8 bfr = *(const short8*)(W + (size_t)(w * 64 + nt * 16 + u) * 256 + k0 + g * 8);
            acc[nt] = __builtin_amdgcn_mfma_f32_16x16x32_bf16(af, bfr, acc[nt], 0, 0, 0);
        }
    }

    float bv[4];
#pragma unroll
    for (int nt = 0; nt < 4; ++nt) bv[nt] = bias[w * 64 + nt * 16 + u];

    float sv[4][4];   // [reg][nt]
#pragma unroll
    for (int reg = 0; reg < 4; ++reg) {
        const int row = rbase + 4 * g + reg;
        float s1 = 0.f, s2 = 0.f;
#pragma unroll
        for (int nt = 0; nt < 4; ++nt) {
            const int col = w * 64 + nt * 16 + u;
            float v = acc[nt][reg] + bv[nt];
            if (act) v = v >= 0.f ? v : 0.01f * v;
            float res = resF ? resF[(size_t)row * 256 + col]
                             : upk((unsigned)resB[(size_t)row * 256 + col]);
            float s = v + res;
            sv[reg][nt] = s;
            s1 += s;
            s2 = fmaf(s, s, s2);
        }
        s1 += __shfl_xor(s1, 1, 64); s2 += __shfl_xor(s2, 1, 64);
        s1 += __shfl_xor(s1, 2, 64); s2 += __shfl_xor(s2, 2, 64);
        s1 += __shfl_xor(s1, 4, 64); s2 += __shfl_xor(s2, 4, 64);
        s1 += __shfl_xor(s1, 8, 64); s2 += __shfl_xor(s2, 8, 64);
        if (u == 0) { red1[w * 16 + 4 * g + reg] = s1; red2[w * 16 + 4 * g + reg] = s2; }
    }
    __syncthreads();

    float gv[4], btv[4];
#pragma unroll
    for (int nt = 0; nt < 4; ++nt) {
        gv[nt]  = gam[w * 64 + nt * 16 + u];
        btv[nt] = bet[w * 64 + nt * 16 + u];
    }
#pragma unroll
    for (int reg = 0; reg < 4; ++reg) {
        const int row = rbase + 4 * g + reg;
        const int rl = 4 * g + reg;
        float S1 = red1[rl] + red1[16 + rl] + red1[32 + rl] + red1[48 + rl];
        float S2 = red2[rl] + red2[16 + rl] + red2[32 + rl] + red2[48 + rl];
        float mu = S1 * (1.f / 256.f);
        float var = S2 * (1.f / 256.f) - mu * mu;
        float rsig = rsqrtf(var + 1e-5f);
#pragma unroll
        for (int nt = 0; nt < 4; ++nt) {
            const int col = w * 64 + nt * 16 + u;
            float o = (sv[reg][nt] - mu) * rsig * gv[nt] + btv[nt];
            if (outF) outF[(size_t)row * 256 + col] = o;
            else      outB[(size_t)row * 256 + col] = (ushort)bf16u(o);
        }
    }
}

extern "C" void kernel_launch(void* const* d_in, const int* in_sizes, int n_in,
                              void* d_out, int out_size, void* d_ws, size_t ws_size,
                              hipStream_t stream) {
    const float* x    = (const float*)d_in[0];
    const int*   mask = (const int*)d_in[1];
    const float* rel  = (const float*)d_in[2];
    const float* Wq   = (const float*)d_in[3];
    const float* Wk   = (const float*)d_in[4];
    const float* Wv   = (const float*)d_in[5];
    const float* pw1  = (const float*)d_in[6];
    const float* pb1  = (const float*)d_in[7];
    const float* pw2  = (const float*)d_in[8];
    const float* pb2  = (const float*)d_in[9];
    const float* Wo   = (const float*)d_in[10];
    const float* bo   = (const float*)d_in[11];
    const float* Wf   = (const float*)d_in[12];
    const float* bf   = (const float*)d_in[13];
    const float* g1   = (const float*)d_in[14];
    const float* be1  = (const float*)d_in[15];
    const float* g2   = (const float*)d_in[16];
    const float* be2  = (const float*)d_in[17];
    float* out = (float*)d_out;

    char* wsb = (char*)d_ws;
    ushort* Qb    = (ushort*)(wsb);                                      // 2 MB
    ushort* Kb    = (ushort*)(wsb + (size_t)( 2 << 20));                 // 2 MB
    ushort* Vt    = (ushort*)(wsb + (size_t)( 4 << 20));                 // 2 MB
    ushort* Yb    = (ushort*)(wsb + (size_t)( 6 << 20));                 // 2 MB
    ushort* Wqkvc = (ushort*)(wsb + (size_t)( 8 << 20));                 // 384 KB
    ushort* Woc   = (ushort*)(wsb + (size_t)( 8 << 20) + (512 << 10));   // 128 KB
    ushort* Wfc   = (ushort*)(wsb + (size_t)( 8 << 20) + (768 << 10));   // 128 KB
    ushort* LUTb  = (ushort*)(wsb + (size_t)( 9 << 20));                 // 8 KB
    ushort* ZZb   = (ushort*)(wsb + (size_t)(10 << 20));                 // 2 MB
    ushort* Dm    = (ushort*)(wsb + (size_t)(12 << 20));                 // 8 MB

    cast_all<<<4417, 256, 0, stream>>>(rel, mask, Wq, Wk, Wv, Wo, Wf,
                                       pw1, pb1, pw2, pb2,
                                       Wqkvc, Woc, Wfc, LUTb, Dm);
    qkv_direct<<<dim3(256, 3), 256, 0, stream>>>(x, Wqkvc, Qb, Kb, Vt);
    attn_mfma<<<dim3(64, 4, 4), 256, 0, stream>>>(Qb, Kb, Vt, Dm, LUTb, Yb);
    gemm_ln<<<256, 256, 0, stream>>>(Yb, Woc, bo, x, nullptr, g1, be1,
                                     nullptr, ZZb, 0);
    gemm_ln<<<256, 256, 0, stream>>>(ZZb, Wfc, bf, nullptr, ZZb, g2, be2,
                                     out, nullptr, 1);
}